// Round 9
// baseline (535.597 us; speedup 1.0000x reference)
//
#include <hip/hip_runtime.h>

// DiffAttn on MI355X, round 16.
// Rounds 9-15: eight schedule variants at 256^2/1-block-per-CU all land at
// 119-141us, MfmaUtil 20-23%. Invariant: single resident block -> when its
// waves wait, the CU idles. m97's 36% came from ~3 co-resident 128^2 blocks
// (TLP covers stalls, m114); m102 shows the same kernel at 1 block/CU drops
// to 13%. Fix: 128^2 tiles, 4 waves, BK=32, 40 KB LDS -> 4 blocks/CU
// (launch_bounds(256,4); ~64 VGPR + 64 acc = 128/wave = 16 waves/SIMD file).
// Persistent (4 subtiles = 64 continuous K-tiles/block), in-pipeline
// epilogue in a disjoint 2 KB/wave buffer, XCD panel decode, grid 1024 =
// exactly one 4-per-CU round. Simple m97-style tile loop: stage(T+1),
// sched_barrier, 8 ds_read + 16 MFMA, vmcnt(0), barrier — TLP does the rest.
// apply_pv / legacy V-GEMM / conversions unchanged (verified).

typedef unsigned short u16;
typedef short    bf16x8 __attribute__((ext_vector_type(8)));
typedef unsigned short u16x8 __attribute__((ext_vector_type(8)));
typedef unsigned short u16x4 __attribute__((ext_vector_type(4)));
typedef float    f32x4  __attribute__((ext_vector_type(4)));

typedef __attribute__((address_space(3))) unsigned int       lds_uint;
typedef __attribute__((address_space(1))) const unsigned int gl_uint;

__device__ __forceinline__ void glds16(const void* g, void* l) {
  __builtin_amdgcn_global_load_lds((gl_uint*)g, (lds_uint*)l, 16, 0, 0);
}

__device__ __forceinline__ u16 to_bf16(float f) {
  unsigned u = __float_as_uint(f);
  return (u16)((u + 0x7FFFu + ((u >> 16) & 1u)) >> 16);  // RNE
}
__device__ __forceinline__ float b2f(u16 h) {
  return __uint_as_float(((unsigned)h) << 16);
}

// ---------------- conversion kernels ----------------

__global__ void cvt_x(const float4* __restrict__ in, u16x4* __restrict__ out, int n4) {
  int i = blockIdx.x * 256 + threadIdx.x;
  if (i >= n4) return;
  float4 v = in[i];
  u16x4 o;
  o[0] = to_bf16(v.x); o[1] = to_bf16(v.y); o[2] = to_bf16(v.z); o[3] = to_bf16(v.w);
  out[i] = o;
}

__global__ void transpose_cvt(const float* __restrict__ in, u16* __restrict__ out,
                              int R, int C) {
  __shared__ float t[64][65];
  int c0 = blockIdx.x * 64, r0 = blockIdx.y * 64;
  int tx = threadIdx.x, ty = threadIdx.y;
  #pragma unroll
  for (int i = 0; i < 64; i += 4)
    t[ty + i][tx] = in[(long)(r0 + ty + i) * C + c0 + tx];
  __syncthreads();
  #pragma unroll
  for (int i = 0; i < 64; i += 4)
    out[(long)(c0 + ty + i) * R + r0 + tx] = to_bf16(t[tx][ty + i]);
}

__global__ void concat2(const float* __restrict__ a, const float* __restrict__ b,
                        float* __restrict__ o, int n) {
  int i = blockIdx.x * 256 + threadIdx.x;
  if (i < n) o[i] = a[i];
  else if (i < 2 * n) o[i] = b[i - n];
}

// GROUP_M=4 swizzle (legacy gemm_nt only).
__device__ __forceinline__ void swizzle_tiles(int& tm, int& tn) {
  int nx = gridDim.x;
  int lin = blockIdx.y * nx + blockIdx.x;
  int span = nx * 4;
  int group = lin / span;
  int ing = lin % span;
  tm = group * 4 + (ing & 3);
  tn = ing >> 2;
}

// ---------------- legacy 128x128 NT GEMM (kept for the V projection) --------
__global__ __launch_bounds__(256, 4) void gemm_nt(
    const u16* __restrict__ A, int lda,
    const u16* __restrict__ B, int ldb,
    u16* __restrict__ C1, u16* __restrict__ C2, int splitN, int ldc,
    int Kd, float scale,
    const float* __restrict__ bias, int biasMode)   // 0 none, 1 per-col, 2 per-row
{
  __shared__ u16 SM[2][8192];
  u16* As = SM[0];
  u16* Bs = SM[1];

  int tid = threadIdx.x;
  int wave = tid >> 6, lane = tid & 63;
  int quad = lane >> 4, ln = lane & 15;
  int wm = wave >> 1, wn = wave & 1;
  int tm, tn;
  swizzle_tiles(tm, tn);
  int c8 = lane >> 3, ml = lane & 7;

  const f32x4 fz = {0.f, 0.f, 0.f, 0.f};
  f32x4 acc[4][4];
  #pragma unroll
  for (int i = 0; i < 4; i++)
    #pragma unroll
    for (int j = 0; j < 4; j++) acc[i][j] = fz;

  const u16* Abase = A + (long)(tm * 128 + ml) * lda + c8 * 8;
  const u16* Bbase = B + (long)(tn * 128 + ml) * ldb + c8 * 8;

  for (int kt = 0; kt < Kd; kt += 64) {
    __syncthreads();
    #pragma unroll
    for (int i = 0; i < 4; i++) {
      int mg = wave * 4 + i;
      glds16(Abase + (long)mg * 8 * lda + kt, &As[mg * 512]);
      glds16(Bbase + (long)mg * 8 * ldb + kt, &Bs[mg * 512]);
    }
    __syncthreads();
    #pragma unroll
    for (int ks = 0; ks < 2; ks++) {
      bf16x8 af[4], bfr[4];
      int c = ks * 4 + quad;
      #pragma unroll
      for (int mt = 0; mt < 4; mt++) {
        int m = wm * 64 + mt * 16 + ln;
        af[mt] = *(const bf16x8*)&As[((m >> 3) * 64 + c * 8 + (m & 7)) * 8];
      }
      #pragma unroll
      for (int nt = 0; nt < 4; nt++) {
        int n = wn * 64 + nt * 16 + ln;
        bfr[nt] = *(const bf16x8*)&Bs[((n >> 3) * 64 + c * 8 + (n & 7)) * 8];
      }
      #pragma unroll
      for (int mt = 0; mt < 4; mt++)
        #pragma unroll
        for (int nt = 0; nt < 4; nt++)
          acc[mt][nt] = __builtin_amdgcn_mfma_f32_16x16x32_bf16(af[mt], bfr[nt], acc[mt][nt], 0, 0, 0);
    }
  }

  int rowBase = tm * 128 + wm * 64;
  int colBase = tn * 128 + wn * 64;
  u16* Cw = C1; int outCol = colBase;
  if (colBase >= splitN) { Cw = C2; outCol = colBase - splitN; }
  u16* eb = &SM[0][0] + wave * 4096;

  __syncthreads();
  #pragma unroll
  for (int mt = 0; mt < 4; mt++) {
    #pragma unroll
    for (int nt = 0; nt < 4; nt++) {
      int colL = nt * 16 + ln;
      float bcol = (biasMode == 1) ? bias[colBase + colL] : 0.f;
      #pragma unroll
      for (int r = 0; r < 4; r++) {
        int rowL = mt * 16 + quad * 4 + r;
        float brow = (biasMode == 2) ? bias[rowBase + rowL] : 0.f;
        float v = acc[mt][nt][r] * scale + bcol + brow;
        eb[rowL * 64 + (((colL >> 3) ^ (rowL & 7)) << 3) + (colL & 7)] = to_bf16(v);
      }
    }
  }
  {
    int row = lane;
    long gr = (long)(rowBase + row) * ldc + outCol;
    #pragma unroll
    for (int c = 0; c < 8; c++) {
      u16x8 ch = *(const u16x8*)&eb[row * 64 + ((c ^ (row & 7)) << 3)];
      *(u16x8*)&Cw[gr + c * 8] = ch;
    }
  }
}

// ============ persistent 128x128 high-occupancy GEMM kernels (BK=32) =========
// 4 waves (2m x 2n), wave output 64x64, acc[4][4] (64 VGPR). LDS 40 KB:
// A dbuf @0/@4096, B dbuf @8192/@12288, eb @16384 + wave*1024 (16x64). u16 idx.
// Chunk = 128 rows x 32 cols, packed: elem(row,col) -> (row>>3)*256 +
// (col>>3)*64 + (row&7)*8 + (col&7); 16-row group = 512 u16, lane-linear
// (lane l writes l*8..l*8+8 via dr=((l>>5)<<3)+(l&7), cg=(l>>3)&3).
// Fragment (row m, k-cols quad*8..+8): b128 @ (m>>3)*256 + quad*64 + (m&7)*8.
// Tile loop: stage(T+1) [2+2 glds16/wave] -> sched_barrier -> 8 ds_read +
// 16 MFMA -> vmcnt(0) -> barrier. 4 blocks/CU provide the latency hiding.

// ---------------- persistent S GEMM: E=exp(S) + per-64col sum partials ------
// grid 1024: g=blk&7 (XCD), r=blk>>3; pan=g+8*(r>>4) (0..63) -> tmg=pan&3,
// z=pan>>2; tn=r&15. Block = 4 subtiles (rows tmg*512 + sub*128), 64 K-tiles.
__global__ __launch_bounds__(256, 4) void gemm_s128p(
    const u16* __restrict__ Q, const u16* __restrict__ K,
    u16* __restrict__ E1, u16* __restrict__ E2,
    float* __restrict__ statsP, float scale)
{
  __shared__ u16 SM[20480];   // 40 KB

  int blk = blockIdx.x;
  int g = blk & 7, r = blk >> 3;
  int pan = g + 8 * (r >> 4);      // 0..63
  int tn = r & 15;
  int tmg = pan & 3, z = pan >> 2; // z 0..15
  int bz = z >> 1, half = z & 1;

  const u16* A = Q + (long)bz * 2097152 + half * 512;
  const u16* B = K + (long)bz * 2097152 + half * 512;
  u16* Ed = (half ? E2 : E1) + (long)bz * 4194304;
  float* sp = statsP + (long)z * 65536;

  int tid = threadIdx.x;
  int wave = tid >> 6, lane = tid & 63, quad = lane >> 4, ln = lane & 15;
  int wm = wave >> 1, wn = wave & 1;
  int dr = ((lane >> 5) << 3) + (lane & 7);
  int cg = (lane >> 3) & 3;

  const f32x4 fz = {0.f, 0.f, 0.f, 0.f};
  f32x4 acc[4][4];
  #pragma unroll
  for (int i = 0; i < 4; i++)
    #pragma unroll
    for (int j = 0; j < 4; j++) acc[i][j] = fz;

  const u16* Ab = A + (long)(tmg * 512 + dr) * 1024 + cg * 8;
  const u16* Bb = B + (long)(tn * 128 + dr) * 1024 + cg * 8;
  u16* eb = SM + 16384 + wave * 1024;

  // prologue: stage tile 0 into buf 0
  #pragma unroll
  for (int i = 0; i < 2; i++) {
    int g16 = wave * 2 + i;
    glds16(Ab + (long)(g16 * 16) * 1024, SM + g16 * 512);
    glds16(Bb + (long)(g16 * 16) * 1024, SM + 8192 + g16 * 512);
  }
  asm volatile("s_waitcnt vmcnt(0)" ::: "memory");
  __builtin_amdgcn_s_barrier();
  __builtin_amdgcn_sched_barrier(0);

  for (int T = 0; T < 64; T++) {
    const u16* Ar = SM + (T & 1) * 4096;
    const u16* Br = SM + 8192 + (T & 1) * 4096;

    // stage T+1 (clamped tail re-stages identical bytes into idle buffer)
    {
      int Tn = (T + 1 < 64) ? T + 1 : 63;
      int sub_n = Tn >> 4, kt_n = (Tn & 15) << 5;
      u16* dA = SM + (Tn & 1) * 4096;
      u16* dB = SM + 8192 + (Tn & 1) * 4096;
      #pragma unroll
      for (int i = 0; i < 2; i++) {
        int g16 = wave * 2 + i;
        glds16(Ab + (long)(sub_n * 128 + g16 * 16) * 1024 + kt_n, dA + g16 * 512);
        glds16(Bb + (long)(g16 * 16) * 1024 + kt_n,               dB + g16 * 512);
      }
    }
    __builtin_amdgcn_sched_barrier(0);

    // fragments + 16 MFMA (compiler-scheduled)
    bf16x8 bfr[4];
    #pragma unroll
    for (int nt = 0; nt < 4; nt++) {
      int n = wn * 64 + nt * 16 + ln;
      bfr[nt] = *(const bf16x8*)(Br + (n >> 3) * 256 + quad * 64 + (n & 7) * 8);
    }
    #pragma unroll
    for (int mt = 0; mt < 4; mt++) {
      int m = wm * 64 + mt * 16 + ln;
      bf16x8 af = *(const bf16x8*)(Ar + (m >> 3) * 256 + quad * 64 + (m & 7) * 8);
      #pragma unroll
      for (int nt = 0; nt < 4; nt++)
        acc[mt][nt] = __builtin_amdgcn_mfma_f32_16x16x32_bf16(af, bfr[nt], acc[mt][nt], 0, 0, 0);
    }

    asm volatile("s_waitcnt vmcnt(0)" ::: "memory");   // T+1 landed
    __builtin_amdgcn_s_barrier();
    __builtin_amdgcn_sched_barrier(0);

    // in-pipeline epilogue each sub boundary (wave-private eb, no barriers)
    if ((T & 15) == 15) {
      int sub = T >> 4;
      int rowB = tmg * 512 + sub * 128 + wm * 64;
      int colB = tn * 128 + wn * 64;
      int kb = tn * 2 + wn;
      #pragma unroll
      for (int c2 = 0; c2 < 4; c2++) {
        #pragma unroll
        for (int nt = 0; nt < 4; nt++) {
          int colL = nt * 16 + ln;
          #pragma unroll
          for (int rr = 0; rr < 4; rr++) {
            int rowL = quad * 4 + rr;
            eb[rowL * 64 + (((colL >> 3) ^ (rowL & 7)) << 3) + (colL & 7)] =
                to_bf16(__expf(acc[c2][nt][rr] * scale));
          }
        }
        {
          int row = lane & 15, hf = lane >> 4;   // 16 rows x 4 col-quarters
          float L = 0.f;
          u16x8 ch[2];
          #pragma unroll
          for (int cc = 0; cc < 2; cc++) {
            int c = hf * 2 + cc;
            ch[cc] = *(const u16x8*)&eb[row * 64 + ((c ^ (row & 7)) << 3)];
            #pragma unroll
            for (int j = 0; j < 8; j++) L += b2f(ch[cc][j]);
          }
          u16* Ep = Ed + (long)(rowB + c2 * 16 + row) * 2048 + colB + hf * 16;
          *(u16x8*)&Ep[0] = ch[0];
          *(u16x8*)&Ep[8] = ch[1];
          L += __shfl_xor(L, 16);
          L += __shfl_xor(L, 32);
          if (hf == 0)
            sp[(rowB + c2 * 16 + row) * 32 + kb] = L;
        }
        #pragma unroll
        for (int j = 0; j < 4; j++) acc[c2][j] = fz;
      }
    }
  }
  asm volatile("s_waitcnt vmcnt(0)" ::: "memory");
}

// ---------------- persistent NT GEMM for the QK projection ------------------
// grid 1024: pan=g+8*(r>>4) (0..63) = tm-pair; tn=r&15; sub 0..1 ->
// tm = pan*2+sub (rows pan*256 + sub*128). K=1024 -> 64 K-tiles/block.
__global__ __launch_bounds__(256, 4) void gemm_nt128p(
    const u16* __restrict__ A, const u16* __restrict__ B,
    u16* __restrict__ C1, u16* __restrict__ C2, int splitN, int ldc,
    const float* __restrict__ bias)
{
  __shared__ u16 SM[20480];   // 40 KB

  int blk = blockIdx.x;
  int g = blk & 7, r = blk >> 3;
  int pan = g + 8 * (r >> 4);      // 0..63
  int tn = r & 15;

  int tid = threadIdx.x;
  int wave = tid >> 6, lane = tid & 63, quad = lane >> 4, ln = lane & 15;
  int wm = wave >> 1, wn = wave & 1;
  int dr = ((lane >> 5) << 3) + (lane & 7);
  int cg = (lane >> 3) & 3;

  const f32x4 fz = {0.f, 0.f, 0.f, 0.f};
  f32x4 acc[4][4];
  #pragma unroll
  for (int i = 0; i < 4; i++)
    #pragma unroll
    for (int j = 0; j < 4; j++) acc[i][j] = fz;

  const u16* Ab = A + (long)(pan * 256 + dr) * 1024 + cg * 8;
  const u16* Bb = B + (long)(tn * 128 + dr) * 1024 + cg * 8;
  u16* eb = SM + 16384 + wave * 1024;

  #pragma unroll
  for (int i = 0; i < 2; i++) {
    int g16 = wave * 2 + i;
    glds16(Ab + (long)(g16 * 16) * 1024, SM + g16 * 512);
    glds16(Bb + (long)(g16 * 16) * 1024, SM + 8192 + g16 * 512);
  }
  asm volatile("s_waitcnt vmcnt(0)" ::: "memory");
  __builtin_amdgcn_s_barrier();
  __builtin_amdgcn_sched_barrier(0);

  for (int T = 0; T < 64; T++) {
    const u16* Ar = SM + (T & 1) * 4096;
    const u16* Br = SM + 8192 + (T & 1) * 4096;

    {
      int Tn = (T + 1 < 64) ? T + 1 : 63;
      int sub_n = Tn >> 5, kt_n = (Tn & 31) << 5;
      u16* dA = SM + (Tn & 1) * 4096;
      u16* dB = SM + 8192 + (Tn & 1) * 4096;
      #pragma unroll
      for (int i = 0; i < 2; i++) {
        int g16 = wave * 2 + i;
        glds16(Ab + (long)(sub_n * 128 + g16 * 16) * 1024 + kt_n, dA + g16 * 512);
        glds16(Bb + (long)(g16 * 16) * 1024 + kt_n,               dB + g16 * 512);
      }
    }
    __builtin_amdgcn_sched_barrier(0);

    bf16x8 bfr[4];
    #pragma unroll
    for (int nt = 0; nt < 4; nt++) {
      int n = wn * 64 + nt * 16 + ln;
      bfr[nt] = *(const bf16x8*)(Br + (n >> 3) * 256 + quad * 64 + (n & 7) * 8);
    }
    #pragma unroll
    for (int mt = 0; mt < 4; mt++) {
      int m = wm * 64 + mt * 16 + ln;
      bf16x8 af = *(const bf16x8*)(Ar + (m >> 3) * 256 + quad * 64 + (m & 7) * 8);
      #pragma unroll
      for (int nt = 0; nt < 4; nt++)
        acc[mt][nt] = __builtin_amdgcn_mfma_f32_16x16x32_bf16(af, bfr[nt], acc[mt][nt], 0, 0, 0);
    }

    asm volatile("s_waitcnt vmcnt(0)" ::: "memory");
    __builtin_amdgcn_s_barrier();
    __builtin_amdgcn_sched_barrier(0);

    if ((T & 31) == 31) {
      int sub = T >> 5;
      int rowB = pan * 256 + sub * 128 + wm * 64;
      int colB = tn * 128 + wn * 64;
      u16* Cw = C1; int outCol = colB;
      if (colB >= splitN) { Cw = C2; outCol = colB - splitN; }
      #pragma unroll
      for (int c2 = 0; c2 < 4; c2++) {
        #pragma unroll
        for (int nt = 0; nt < 4; nt++) {
          int colL = nt * 16 + ln;
          float bcol = bias[colB + colL];
          #pragma unroll
          for (int rr = 0; rr < 4; rr++) {
            int rowL = quad * 4 + rr;
            eb[rowL * 64 + (((colL >> 3) ^ (rowL & 7)) << 3) + (colL & 7)] =
                to_bf16(acc[c2][nt][rr] + bcol);
          }
        }
        {
          int row = lane & 15, hf = lane >> 4;
          u16x8 ch[2];
          #pragma unroll
          for (int cc = 0; cc < 2; cc++) {
            int c = hf * 2 + cc;
            ch[cc] = *(const u16x8*)&eb[row * 64 + ((c ^ (row & 7)) << 3)];
          }
          long gr = (long)(rowB + c2 * 16 + row) * ldc + outCol + hf * 16;
          *(u16x8*)&Cw[gr]     = ch[0];
          *(u16x8*)&Cw[gr + 8] = ch[1];
        }
        #pragma unroll
        for (int j = 0; j < 4; j++) acc[c2][j] = fz;
      }
    }
  }
  asm volatile("s_waitcnt vmcnt(0)" ::: "memory");
}

// ---------------- stats reduce: 32 partials -> inv-denominator ----------------
__global__ void stats_reduce(const float* __restrict__ sp, float* __restrict__ so,
                             const float* __restrict__ lamPtr) {
  int gid = blockIdx.x * 256 + threadIdx.x;   // 0..32767
  const float* p = sp + (long)gid * 32;
  float L = 0.f;
  #pragma unroll
  for (int kb = 0; kb < 32; kb++) L += p[kb];
  int half = (gid >> 11) & 1;
  so[gid] = (half ? lamPtr[0] : 1.0f) / L;
}

// ---------------- apply: O = (E1*i1 - E2*i2) @ V ----------------
// (verified round-10 version, unchanged)
__global__ __launch_bounds__(512, 2) void apply_pv(
    const u16* __restrict__ E1, const u16* __restrict__ E2,
    const u16* __restrict__ VT, const float* __restrict__ inv,
    float* __restrict__ Out)
{
  __shared__ u16 Vs[2][32768];    // 2 x [512 d][64 k] packed subtile, 128 KB
  __shared__ u16 Pb[2][4096];     // 2 x [64 q][64 k] packed subtile, 16 KB
  __shared__ float i1s[64], i2s[64];

  const int NT = 32;
  int b = blockIdx.x & 7, qt = blockIdx.x >> 3;
  int q0 = qt * 64;
  int tid = threadIdx.x;
  int wave = tid >> 6, lane = tid & 63, quad = lane >> 4, ln = lane & 15;
  int c8 = lane >> 3, ml = lane & 7;
  int r = tid >> 3, cg8 = tid & 7;            // P producer mapping: 64 rows x 8 col-groups

  const u16* e1p = E1 + ((long)b * 2048 + q0 + r) * 2048 + cg8 * 8;
  const u16* e2p = E2 + ((long)b * 2048 + q0 + r) * 2048 + cg8 * 8;
  const u16* Vbase = VT + (long)b * 2048;     // row stride 16384 (u16)
  int pw = (r >> 3) * 512 + cg8 * 64 + (r & 7) * 8;   // packed P write idx (u16)

  const f32x4 fz = {0.f, 0.f, 0.f, 0.f};
  f32x4 acc[4][4];
  #pragma unroll
  for (int i = 0; i < 4; i++)
    #pragma unroll
    for (int j = 0; j < 4; j++) acc[i][j] = fz;

  // ---- prologue ----
  if (tid < 64)       i1s[tid]       = inv[(long)(b * 2 + 0) * 2048 + q0 + tid];
  else if (tid < 128) i2s[tid - 64]  = inv[(long)(b * 2 + 1) * 2048 + q0 + (tid - 64)];
  u16x8 a1 = *(const u16x8*)(e1p);            // E(0), compiler-tracked
  u16x8 a2 = *(const u16x8*)(e2p);
  __builtin_amdgcn_sched_barrier(0);
  #pragma unroll
  for (int i = 0; i < 8; i++) {               // V(0) -> Vs[0]
    int dg = wave * 8 + i;
    glds16(Vbase + (long)(dg * 8 + ml) * 16384 + c8 * 8, &Vs[0][dg * 512]);
  }
  __builtin_amdgcn_sched_barrier(0);
  asm volatile("s_waitcnt lgkmcnt(0)" ::: "memory");   // i1s/i2s stores done
  __builtin_amdgcn_s_barrier();                        // i1s visible
  __builtin_amdgcn_sched_barrier(0);
  float i1 = i1s[r], i2 = i2s[r];
  {
    u16x8 o;
    #pragma unroll
    for (int j = 0; j < 8; j++)
      o[j] = to_bf16(b2f(a1[j]) * i1 - b2f(a2[j]) * i2);
    *(u16x8*)&Pb[0][pw] = o;                  // P(0)
  }
  a1 = *(const u16x8*)(e1p + 64);             // E(1)
  a2 = *(const u16x8*)(e2p + 64);
  __builtin_amdgcn_sched_barrier(0);
  asm volatile("s_waitcnt lgkmcnt(0)" ::: "memory");   // P(0) write done
  asm volatile("s_waitcnt vmcnt(2)" ::: "memory");     // V(0) landed, E(1) flying
  __builtin_amdgcn_sched_barrier(0);
  __builtin_amdgcn_s_barrier();
  __builtin_amdgcn_sched_barrier(0);

  // ---- main loop ----
  for (int t = 0; t < NT; t++) {
    const int p = t & 1;
    const u16* Vr = &Vs[p][0];
    const u16* Pr = &Pb[p][0];
    u16* Vw = &Vs[p ^ 1][0];
    u16* Pw = &Pb[p ^ 1][0];
    int ktv = ((t + 1 < NT) ? (t + 1) : (NT - 1)) << 6;   // V(t+1)
    int kte = ((t + 2 < NT) ? (t + 2) : (NT - 1)) << 6;   // E(t+2)
    bf16x8 vf[2][4];

    #pragma unroll
    for (int q = 0; q < 4; q++) {
      bf16x8 pf[2];
      #pragma unroll
      for (int ks = 0; ks < 2; ks++) {
        int m = q * 16 + ln;
        pf[ks] = *(const bf16x8*)&Pr[((m >> 3) * 64 + (ks * 4 + quad) * 8 + (m & 7)) * 8];
      }
      if (q == 0) {
        #pragma unroll
        for (int ks = 0; ks < 2; ks++)
          #pragma unroll
          for (int nt = 0; nt < 4; nt++) {
            int d = wave * 64 + nt * 16 + ln;
            vf[ks][nt] = *(const bf16x8*)&Vr[((d >> 3) * 64 + (ks * 4 + quad) * 8 + (d & 7)) * 8];
          }
      }
      // stage V(t+1): 2 glds16 per wave per phase
      #pragma unroll
      for (int i = 0; i < 2; i++) {
        int dg = wave * 8 + q * 2 + i;
        glds16(Vbase + (long)(dg * 8 + ml) * 16384 + ktv + c8 * 8, Vw + dg * 512);
      }
      if (q == 3) {
        __builtin_amdgcn_sched_barrier(0);
        // compiler inserts the wait for a1/a2 (E(t+1)) here; V(t+1)x8 stay out
        u16x8 o;
        #pragma unroll
        for (int j = 0; j < 8; j++)
          o[j] = to_bf16(b2f(a1[j]) * i1 - b2f(a2[j]) * i2);
        *(u16x8*)&Pw[pw] = o;                             // P(t+1)
        a1 = *(const u16x8*)(e1p + kte);                  // E(t+2)
        a2 = *(const u16x8*)(e2p + kte);
      }
      __builtin_amdgcn_sched_barrier(0);
      __builtin_amdgcn_s_barrier();
      asm volatile("s_waitcnt lgkmcnt(0)" ::: "memory");
      __builtin_amdgcn_sched_barrier(0);
      __builtin_amdgcn_s_setprio(1);
      #pragma unroll
      for (int ks = 0; ks < 2; ks++)
        #pragma unroll
        for (int nt = 0; nt < 4; nt++)
          acc[q][nt] = __builtin_amdgcn_mfma_f32_16x16x32_bf16(pf[ks], vf[ks][nt], acc[q][nt], 0, 0, 0);
      __builtin_amdgcn_s_setprio(0);
      __builtin_amdgcn_sched_barrier(0);
      if (q == 3) asm volatile("s_waitcnt vmcnt(2)" ::: "memory");  // V(t+1) landed
      __builtin_amdgcn_s_barrier();
      __builtin_amdgcn_sched_barrier(0);
    }
  }

  #pragma unroll
  for (int mt = 0; mt < 4; mt++)
    #pragma unroll
    for (int nt = 0; nt < 4; nt++)
      #pragma unroll
      for (int r2 = 0; r2 < 4; r2++)
        Out[((long)b * 2048 + q0 + mt * 16 + quad * 4 + r2) * 512 + wave * 64 + nt * 16 + ln] =
            acc[mt][nt][r2];
}

// ---------------- launch ----------------

extern "C" void kernel_launch(void* const* d_in, const int* in_sizes, int n_in,
                              void* d_out, int out_size, void* d_ws, size_t ws_size,
                              hipStream_t stream)
{
  const float* X   = (const float*)d_in[0];
  const float* lam = (const float*)d_in[1];
  const float* Wq  = (const float*)d_in[2];
  const float* bq  = (const float*)d_in[3];
  const float* Wk  = (const float*)d_in[4];
  const float* bk  = (const float*)d_in[5];
  const float* Wv  = (const float*)d_in[6];
  const float* bv  = (const float*)d_in[7];
  float* Out = (float*)d_out;
  char* ws = (char*)d_ws;

  u16*  WqkT   = (u16*)(ws + 0);           //  4 MB [2048][1024]
  u16*  WvT    = (u16*)(ws + 4194304);     //  1 MB [512][1024]
  float* bqk   = (float*)(ws + 5242880);   //  8 KB [2048]
  u16*  Qb     = (u16*)(ws + 6291456);     // 32 MB [16384][1024]
  u16*  Kb     = (u16*)(ws + 39845888);    // 32 MB [16384][1024]
  u16*  VTb    = (u16*)(ws + 73400320);    // 16 MB [512][16384]
  u16*  Xb     = (u16*)(ws + 90177536);    // 32 MB [16384][1024]
  u16*  E1     = (u16*)(ws + 90177536);    // 64 MB, overlaps Xb (Xb dead first)
  u16*  E2     = (u16*)(ws + 157286400);   // 64 MB
  float* statsP= (float*)(ws + 224395264); //  4 MB [8][2][2048][32]
  float* invD  = (float*)(ws + 228589568); // 128 KB [8][2][2048]

  cvt_x<<<16384, 256, 0, stream>>>((const float4*)X, (u16x4*)Xb, 4194304);
  transpose_cvt<<<dim3(16, 16), dim3(64, 4), 0, stream>>>(Wq, WqkT, 1024, 1024);
  transpose_cvt<<<dim3(16, 16), dim3(64, 4), 0, stream>>>(Wk, WqkT + 1024 * 1024, 1024, 1024);
  transpose_cvt<<<dim3(8, 16),  dim3(64, 4), 0, stream>>>(Wv, WvT, 1024, 512);
  concat2<<<8, 256, 0, stream>>>(bq, bk, bqk, 1024);

  // [Q|K] = Xb @ WqkT^T + bqk, persistent high-occupancy 128^2 tiles
  gemm_nt128p<<<1024, 256, 0, stream>>>(Xb, WqkT, Qb, Kb, 1024, 1024, bqk);
  // V^T[d][m] = sum_e WvT[d][e]*Xb[m][e] + bv[d]  (legacy 128^2 kernel)
  gemm_nt<<<dim3(128, 4), 256, 0, stream>>>(WvT, 1024, Xb, 1024,
                                            VTb, VTb, 1 << 30, 16384,
                                            1024, 1.0f, bv, 2);

  const float s = 0.044194173824159216f;  // 1/sqrt(512)
  gemm_s128p<<<1024, 256, 0, stream>>>(Qb, Kb, E1, E2, statsP, s);

  stats_reduce<<<128, 256, 0, stream>>>(statsP, invD, lam);
  apply_pv<<<256, 512, 0, stream>>>(E1, E2, VTb, invD, Out);
}